// Round 1
// baseline (1850.597 us; speedup 1.0000x reference)
//
#include <hip/hip_runtime.h>

#define N_NODES 100000
#define N_EDGES 1600000
#define IN_C 165
#define HID_C 256
#define OUT_C 2

#define NT 16          // nodes per block in fused GEMM
#define ROWLEN 352     // LDS row stride (floats): [0,165)=mean, [168,333)=x, rest pad

// ---------------------------------------------------------------------------
// Workspace layout (floats):
//   deg  : [0,       N)        in-degree (float)
//   acc2 : [N,       3N)       layer-2 aggregated y (2 per node)
//   agg1 : [3N,      168N)     layer-1 neighbor sum (165 per node)
//   yz   : [168N,    172N)     per-node [y0,y1,z0,z1]  y=h@W2_l, z=h@W2_r
// First 168N floats must be zeroed each launch (one memset).
// ---------------------------------------------------------------------------

__global__ void k_deg(const int* __restrict__ dst, float* __restrict__ deg) {
    int e = blockIdx.x * blockDim.x + threadIdx.x;
    if (e < N_EDGES) atomicAdd(&deg[dst[e]], 1.0f);
}

// agg1[dst] += x[src], one thread per (edge, channel)
__global__ void k_scatter1(const int* __restrict__ src, const int* __restrict__ dst,
                           const float* __restrict__ x, float* __restrict__ agg1) {
    unsigned idx = blockIdx.x * blockDim.x + threadIdx.x;
    if (idx >= (unsigned)N_EDGES * IN_C) return;
    unsigned e = idx / IN_C;
    int c = (int)(idx - e * IN_C);
    int s = src[e], d = dst[e];
    atomicAdd(&agg1[d * IN_C + c], x[s * IN_C + c]);
}

// Fused: h = relu(mean1 @ W1_l + b1 + x @ W1_r), then
//        y = h @ W2_l, z = h @ W2_r  (2 cols each) -> yz[n][4]
// Block: 256 threads (thread = output col), NT node-rows staged in LDS.
__launch_bounds__(256)
__global__ void k_gemm1(const float* __restrict__ agg1, const float* __restrict__ x,
                        const float* __restrict__ deg,
                        const float* __restrict__ W1l, const float* __restrict__ b1,
                        const float* __restrict__ W1r,
                        const float* __restrict__ W2l, const float* __restrict__ W2r,
                        float* __restrict__ yz) {
    __shared__ __align__(16) float smem[NT * ROWLEN];   // 22.5 KB; reused for h transpose
    __shared__ float invd_s[NT];
    const int tid = threadIdx.x;
    const int node0 = blockIdx.x * NT;

    if (tid < NT) {
        int n = node0 + tid;
        float d = (n < N_NODES) ? deg[n] : 1.0f;
        invd_s[tid] = 1.0f / fmaxf(d, 1.0f);
    }
    __syncthreads();

    // stage [mean | pad | x | pad] rows
    for (int idx = tid; idx < NT * 336; idx += 256) {
        int i = idx / 336;
        int k = idx - i * 336;
        int n = node0 + i;
        float v = 0.0f;
        if (n < N_NODES) {
            if (k < IN_C) v = agg1[n * IN_C + k] * invd_s[i];
            else if (k >= 168 && k < 168 + IN_C) v = x[n * IN_C + (k - 168)];
        }
        smem[i * ROWLEN + k] = v;
    }
    __syncthreads();

    float acc[NT];
#pragma unroll
    for (int i = 0; i < NT; ++i) acc[i] = b1[tid];

    // mean part: k = 0..164  (41 float4 blocks + 1 scalar)
    for (int kb = 0; kb < 41; ++kb) {
        float w0 = W1l[(4 * kb + 0) * HID_C + tid];
        float w1 = W1l[(4 * kb + 1) * HID_C + tid];
        float w2 = W1l[(4 * kb + 2) * HID_C + tid];
        float w3 = W1l[(4 * kb + 3) * HID_C + tid];
#pragma unroll
        for (int i = 0; i < NT; ++i) {
            float4 v = *(const float4*)&smem[i * ROWLEN + 4 * kb];
            acc[i] = fmaf(v.x, w0, fmaf(v.y, w1, fmaf(v.z, w2, fmaf(v.w, w3, acc[i]))));
        }
    }
    {
        float w = W1l[164 * HID_C + tid];
#pragma unroll
        for (int i = 0; i < NT; ++i) acc[i] = fmaf(smem[i * ROWLEN + 164], w, acc[i]);
    }
    // root part: smem offset 168..332
    for (int kb = 0; kb < 41; ++kb) {
        float w0 = W1r[(4 * kb + 0) * HID_C + tid];
        float w1 = W1r[(4 * kb + 1) * HID_C + tid];
        float w2 = W1r[(4 * kb + 2) * HID_C + tid];
        float w3 = W1r[(4 * kb + 3) * HID_C + tid];
#pragma unroll
        for (int i = 0; i < NT; ++i) {
            float4 v = *(const float4*)&smem[i * ROWLEN + 168 + 4 * kb];
            acc[i] = fmaf(v.x, w0, fmaf(v.y, w1, fmaf(v.z, w2, fmaf(v.w, w3, acc[i]))));
        }
    }
    {
        float w = W1r[164 * HID_C + tid];
#pragma unroll
        for (int i = 0; i < NT; ++i) acc[i] = fmaf(smem[i * ROWLEN + 168 + 164], w, acc[i]);
    }
#pragma unroll
    for (int i = 0; i < NT; ++i) acc[i] = fmaxf(acc[i], 0.0f);   // h values

    // ---- epilogue: y = h@W2_l, z = h@W2_r via LDS transpose + wave reduce ----
    __syncthreads();
#pragma unroll
    for (int i = 0; i < NT; ++i) smem[i * 257 + tid] = acc[i];   // h_s stride 257
    __syncthreads();

    const int lane = tid & 63;
    const int w = tid >> 6;          // wave id 0..3, each handles 4 nodes
    float wl0[4], wl1[4], wr0[4], wr1[4];
#pragma unroll
    for (int j = 0; j < 4; ++j) {
        int c = lane + 64 * j;
        wl0[j] = W2l[c * 2 + 0]; wl1[j] = W2l[c * 2 + 1];
        wr0[j] = W2r[c * 2 + 0]; wr1[j] = W2r[c * 2 + 1];
    }
#pragma unroll
    for (int ii = 0; ii < 4; ++ii) {
        int i = w * 4 + ii;
        float y0 = 0.f, y1 = 0.f, z0 = 0.f, z1 = 0.f;
#pragma unroll
        for (int j = 0; j < 4; ++j) {
            float hv = smem[i * 257 + lane + 64 * j];
            y0 = fmaf(hv, wl0[j], y0); y1 = fmaf(hv, wl1[j], y1);
            z0 = fmaf(hv, wr0[j], z0); z1 = fmaf(hv, wr1[j], z1);
        }
#pragma unroll
        for (int off = 32; off >= 1; off >>= 1) {
            y0 += __shfl_xor(y0, off); y1 += __shfl_xor(y1, off);
            z0 += __shfl_xor(z0, off); z1 += __shfl_xor(z1, off);
        }
        if (lane == 0) {
            int n = node0 + i;
            if (n < N_NODES) {
                yz[n * 4 + 0] = y0; yz[n * 4 + 1] = y1;
                yz[n * 4 + 2] = z0; yz[n * 4 + 3] = z1;
            }
        }
    }
}

// acc2[dst] += y[src]   (2 channels)
__global__ void k_scatter2(const int* __restrict__ src, const int* __restrict__ dst,
                           const float* __restrict__ yz, float* __restrict__ acc2) {
    int e = blockIdx.x * blockDim.x + threadIdx.x;
    if (e >= N_EDGES) return;
    int s = src[e], d = dst[e];
    float2 y = *(const float2*)&yz[s * 4];
    atomicAdd(&acc2[d * 2 + 0], y.x);
    atomicAdd(&acc2[d * 2 + 1], y.y);
}

__global__ void k_final(const float* __restrict__ acc2, const float* __restrict__ deg,
                        const float* __restrict__ yz, const float* __restrict__ b2,
                        float* __restrict__ out) {
    int n = blockIdx.x * blockDim.x + threadIdx.x;
    if (n >= N_NODES) return;
    float invd = 1.0f / fmaxf(deg[n], 1.0f);
    float2 o;
    o.x = acc2[n * 2 + 0] * invd + b2[0] + yz[n * 4 + 2];
    o.y = acc2[n * 2 + 1] * invd + b2[1] + yz[n * 4 + 3];
    *(float2*)&out[n * 2] = o;
}

extern "C" void kernel_launch(void* const* d_in, const int* in_sizes, int n_in,
                              void* d_out, int out_size, void* d_ws, size_t ws_size,
                              hipStream_t stream) {
    const float* x   = (const float*)d_in[0];
    const int*   ei  = (const int*)d_in[1];          // [2][E] int32
    const int*   src = ei;
    const int*   dst = ei + N_EDGES;
    const float* W1l = (const float*)d_in[2];
    const float* b1  = (const float*)d_in[3];
    const float* W1r = (const float*)d_in[4];
    const float* W2l = (const float*)d_in[5];
    const float* b2  = (const float*)d_in[6];
    const float* W2r = (const float*)d_in[7];
    float* out = (float*)d_out;

    float* ws   = (float*)d_ws;
    float* deg  = ws;
    float* acc2 = ws + (size_t)N_NODES;
    float* agg1 = ws + (size_t)3 * N_NODES;
    float* yz   = ws + (size_t)168 * N_NODES;

    // zero deg + acc2 + agg1 (yz fully overwritten before read)
    hipMemsetAsync(ws, 0, (size_t)168 * N_NODES * sizeof(float), stream);

    k_deg<<<(N_EDGES + 255) / 256, 256, 0, stream>>>(dst, deg);

    unsigned total1 = (unsigned)N_EDGES * IN_C;
    k_scatter1<<<(total1 + 255) / 256, 256, 0, stream>>>(src, dst, x, agg1);

    k_gemm1<<<(N_NODES + NT - 1) / NT, 256, 0, stream>>>(agg1, x, deg, W1l, b1, W1r,
                                                         W2l, W2r, yz);

    k_scatter2<<<(N_EDGES + 255) / 256, 256, 0, stream>>>(src, dst, yz, acc2);

    k_final<<<(N_NODES + 255) / 256, 256, 0, stream>>>(acc2, deg, yz, b2, out);
}

// Round 2
// 974.849 us; speedup vs baseline: 1.8983x; 1.8983x over previous
//
#include <hip/hip_runtime.h>

#define N_NODES 100000
#define N_EDGES 1600000
#define IN_C 165
#define HID_C 256
#define OUT_C 2

#define NT 16          // nodes per block in fused GEMM
#define ROWLEN 352     // LDS row stride (floats): [0,165)=mean, [168,333)=x, rest pad

// ---------------------------------------------------------------------------
// Workspace layout (int32 units):
//   deg    : [0,        100000)        in-degree (int)
//   rowptr : [100000,   200001)        CSR row offsets
//   cursor : [200004,   300004)        fill cursors (exclusive prefix copy)
//   csr    : [300004,  1900004)        CSR src indices
//   agg1   : [1900004, 18400004)       (float) mean-aggregated x  [N][165]
//   yz     : [18400004, 18800004)      (float) per-node [y0,y1,z0,z1]
// Only deg needs zeroing (400 KB memset).
// ---------------------------------------------------------------------------

#define OFF_DEG    0
#define OFF_ROWPTR 100000
#define OFF_CURSOR 200004
#define OFF_CSR    300004
#define OFF_AGG1   1900004
#define OFF_YZ     18400004

__global__ void k_deg(const int* __restrict__ dst, int* __restrict__ deg) {
    int e = blockIdx.x * blockDim.x + threadIdx.x;
    if (e < N_EDGES) atomicAdd(&deg[dst[e]], 1);
}

// Single-block scan: rowptr (exclusive->inclusive at +1) and cursor (=exclusive).
#define SCAN_T 1024
#define SCAN_ITEMS 8
#define SCAN_CHUNK (SCAN_T * SCAN_ITEMS)
__launch_bounds__(SCAN_T)
__global__ void k_scan(const int* __restrict__ deg, int* __restrict__ rowptr,
                       int* __restrict__ cursor) {
    __shared__ int wsums[16];
    __shared__ int wprefix[16];
    const int tid = threadIdx.x;
    const int lane = tid & 63;
    const int wid = tid >> 6;
    int carry = 0;
    if (tid == 0) rowptr[0] = 0;
    for (int base = 0; base < N_NODES; base += SCAN_CHUNK) {
        int idx0 = base + tid * SCAN_ITEMS;
        int l[SCAN_ITEMS];
        int run = 0;
#pragma unroll
        for (int j = 0; j < SCAN_ITEMS; ++j) {
            int idx = idx0 + j;
            int v = (idx < N_NODES) ? deg[idx] : 0;
            run += v;
            l[j] = run;                       // thread-local inclusive
        }
        int tsum = run;
        // wave inclusive scan of tsum
        int v = tsum;
#pragma unroll
        for (int off = 1; off < 64; off <<= 1) {
            int t = __shfl_up(v, off);
            if (lane >= off) v += t;
        }
        int wv_excl = v - tsum;
        if (lane == 63) wsums[wid] = v;
        __syncthreads();
        if (wid == 0) {
            int s = (lane < 16) ? wsums[lane] : 0;
#pragma unroll
            for (int off = 1; off < 16; off <<= 1) {
                int t = __shfl_up(s, off);
                if (lane >= off) s += t;
            }
            if (lane < 16) wprefix[lane] = s;
        }
        __syncthreads();
        int waveoff = (wid > 0) ? wprefix[wid - 1] : 0;
        int chunk_total = wprefix[15];
        int tbase = carry + waveoff + wv_excl;
#pragma unroll
        for (int j = 0; j < SCAN_ITEMS; ++j) {
            int idx = idx0 + j;
            if (idx < N_NODES) {
                rowptr[idx + 1] = tbase + l[j];
                cursor[idx] = tbase + (j ? l[j - 1] : 0);
            }
        }
        carry += chunk_total;
        __syncthreads();   // protect wsums/wprefix for next iter
    }
}

__global__ void k_fill(const int* __restrict__ src, const int* __restrict__ dst,
                       int* __restrict__ cursor, int* __restrict__ csr) {
    int e = blockIdx.x * blockDim.x + threadIdx.x;
    if (e >= N_EDGES) return;
    int d = dst[e];
    int pos = atomicAdd(&cursor[d], 1);
    csr[pos] = src[e];
}

// One wave per node: mean-aggregate neighbor x rows. Lane owns channels
// {lane, lane+64, lane+128(<165)}. Writes the MEAN directly.
__global__ void k_agg1(const int* __restrict__ rowptr, const int* __restrict__ csr,
                       const float* __restrict__ x, float* __restrict__ agg1) {
    int gw = (blockIdx.x * blockDim.x + threadIdx.x) >> 6;
    if (gw >= N_NODES) return;
    const int lane = threadIdx.x & 63;
    int beg = rowptr[gw], end = rowptr[gw + 1];
    float a0 = 0.f, a1 = 0.f, a2 = 0.f;
    for (int i = beg; i < end; ++i) {
        int s = csr[i];
        const float* xr = x + (size_t)s * IN_C;
        a0 += xr[lane];
        a1 += xr[lane + 64];
        if (lane < IN_C - 128) a2 += xr[lane + 128];
    }
    float invd = 1.0f / fmaxf((float)(end - beg), 1.0f);
    float* o = agg1 + (size_t)gw * IN_C;
    o[lane] = a0 * invd;
    o[lane + 64] = a1 * invd;
    if (lane < IN_C - 128) o[lane + 128] = a2 * invd;
}

// Fused: h = relu(mean @ W1_l + b1 + x @ W1_r), then
//        y = h @ W2_l, z = h @ W2_r  (2 cols each) -> yz[n][4]
__launch_bounds__(256)
__global__ void k_gemm1(const float* __restrict__ agg1, const float* __restrict__ x,
                        const float* __restrict__ W1l, const float* __restrict__ b1,
                        const float* __restrict__ W1r,
                        const float* __restrict__ W2l, const float* __restrict__ W2r,
                        float* __restrict__ yz) {
    __shared__ __align__(16) float smem[NT * ROWLEN];   // 22.5 KB; reused for h transpose
    const int tid = threadIdx.x;
    const int node0 = blockIdx.x * NT;

    // stage [mean | pad | x | pad] rows
    for (int idx = tid; idx < NT * 336; idx += 256) {
        int i = idx / 336;
        int k = idx - i * 336;
        int n = node0 + i;
        float v = 0.0f;
        if (n < N_NODES) {
            if (k < IN_C) v = agg1[(size_t)n * IN_C + k];
            else if (k >= 168 && k < 168 + IN_C) v = x[(size_t)n * IN_C + (k - 168)];
        }
        smem[i * ROWLEN + k] = v;
    }
    __syncthreads();

    float acc[NT];
#pragma unroll
    for (int i = 0; i < NT; ++i) acc[i] = b1[tid];

    // mean part: k = 0..164  (41 float4 blocks + 1 scalar)
    for (int kb = 0; kb < 41; ++kb) {
        float w0 = W1l[(4 * kb + 0) * HID_C + tid];
        float w1 = W1l[(4 * kb + 1) * HID_C + tid];
        float w2 = W1l[(4 * kb + 2) * HID_C + tid];
        float w3 = W1l[(4 * kb + 3) * HID_C + tid];
#pragma unroll
        for (int i = 0; i < NT; ++i) {
            float4 v = *(const float4*)&smem[i * ROWLEN + 4 * kb];
            acc[i] = fmaf(v.x, w0, fmaf(v.y, w1, fmaf(v.z, w2, fmaf(v.w, w3, acc[i]))));
        }
    }
    {
        float w = W1l[164 * HID_C + tid];
#pragma unroll
        for (int i = 0; i < NT; ++i) acc[i] = fmaf(smem[i * ROWLEN + 164], w, acc[i]);
    }
    // root part: smem offset 168..332
    for (int kb = 0; kb < 41; ++kb) {
        float w0 = W1r[(4 * kb + 0) * HID_C + tid];
        float w1 = W1r[(4 * kb + 1) * HID_C + tid];
        float w2 = W1r[(4 * kb + 2) * HID_C + tid];
        float w3 = W1r[(4 * kb + 3) * HID_C + tid];
#pragma unroll
        for (int i = 0; i < NT; ++i) {
            float4 v = *(const float4*)&smem[i * ROWLEN + 168 + 4 * kb];
            acc[i] = fmaf(v.x, w0, fmaf(v.y, w1, fmaf(v.z, w2, fmaf(v.w, w3, acc[i]))));
        }
    }
    {
        float w = W1r[164 * HID_C + tid];
#pragma unroll
        for (int i = 0; i < NT; ++i) acc[i] = fmaf(smem[i * ROWLEN + 168 + 164], w, acc[i]);
    }
#pragma unroll
    for (int i = 0; i < NT; ++i) acc[i] = fmaxf(acc[i], 0.0f);   // h values

    // ---- epilogue: y = h@W2_l, z = h@W2_r via LDS transpose + wave reduce ----
    __syncthreads();
#pragma unroll
    for (int i = 0; i < NT; ++i) smem[i * 257 + tid] = acc[i];   // h_s stride 257
    __syncthreads();

    const int lane = tid & 63;
    const int w = tid >> 6;          // wave id 0..3, each handles 4 nodes
    float wl0[4], wl1[4], wr0[4], wr1[4];
#pragma unroll
    for (int j = 0; j < 4; ++j) {
        int c = lane + 64 * j;
        wl0[j] = W2l[c * 2 + 0]; wl1[j] = W2l[c * 2 + 1];
        wr0[j] = W2r[c * 2 + 0]; wr1[j] = W2r[c * 2 + 1];
    }
#pragma unroll
    for (int ii = 0; ii < 4; ++ii) {
        int i = w * 4 + ii;
        float y0 = 0.f, y1 = 0.f, z0 = 0.f, z1 = 0.f;
#pragma unroll
        for (int j = 0; j < 4; ++j) {
            float hv = smem[i * 257 + lane + 64 * j];
            y0 = fmaf(hv, wl0[j], y0); y1 = fmaf(hv, wl1[j], y1);
            z0 = fmaf(hv, wr0[j], z0); z1 = fmaf(hv, wr1[j], z1);
        }
#pragma unroll
        for (int off = 32; off >= 1; off >>= 1) {
            y0 += __shfl_xor(y0, off); y1 += __shfl_xor(y1, off);
            z0 += __shfl_xor(z0, off); z1 += __shfl_xor(z1, off);
        }
        if (lane == 0) {
            int n = node0 + i;
            if (n < N_NODES) {
                yz[n * 4 + 0] = y0; yz[n * 4 + 1] = y1;
                yz[n * 4 + 2] = z0; yz[n * 4 + 3] = z1;
            }
        }
    }
}

// One wave per node: out = mean(y[neighbors]) + b2 + z[node]
__global__ void k_layer2(const int* __restrict__ rowptr, const int* __restrict__ csr,
                         const float* __restrict__ yz, const float* __restrict__ b2,
                         float* __restrict__ out) {
    int n = (blockIdx.x * blockDim.x + threadIdx.x) >> 6;
    if (n >= N_NODES) return;
    const int lane = threadIdx.x & 63;
    int beg = rowptr[n], end = rowptr[n + 1];
    float y0 = 0.f, y1 = 0.f;
    for (int i = beg + lane; i < end; i += 64) {
        int s = csr[i];
        float2 v = *(const float2*)&yz[s * 4];
        y0 += v.x; y1 += v.y;
    }
#pragma unroll
    for (int off = 32; off >= 1; off >>= 1) {
        y0 += __shfl_xor(y0, off);
        y1 += __shfl_xor(y1, off);
    }
    if (lane == 0) {
        float invd = 1.0f / fmaxf((float)(end - beg), 1.0f);
        float2 o;
        o.x = y0 * invd + b2[0] + yz[n * 4 + 2];
        o.y = y1 * invd + b2[1] + yz[n * 4 + 3];
        *(float2*)&out[n * 2] = o;
    }
}

extern "C" void kernel_launch(void* const* d_in, const int* in_sizes, int n_in,
                              void* d_out, int out_size, void* d_ws, size_t ws_size,
                              hipStream_t stream) {
    const float* x   = (const float*)d_in[0];
    const int*   ei  = (const int*)d_in[1];          // [2][E] int32
    const int*   src = ei;
    const int*   dst = ei + N_EDGES;
    const float* W1l = (const float*)d_in[2];
    const float* b1  = (const float*)d_in[3];
    const float* W1r = (const float*)d_in[4];
    const float* W2l = (const float*)d_in[5];
    const float* b2  = (const float*)d_in[6];
    const float* W2r = (const float*)d_in[7];
    float* out = (float*)d_out;

    int*   wsi    = (int*)d_ws;
    int*   deg    = wsi + OFF_DEG;
    int*   rowptr = wsi + OFF_ROWPTR;
    int*   cursor = wsi + OFF_CURSOR;
    int*   csr    = wsi + OFF_CSR;
    float* agg1   = (float*)(wsi + OFF_AGG1);
    float* yz     = (float*)(wsi + OFF_YZ);

    hipMemsetAsync(deg, 0, N_NODES * sizeof(int), stream);

    k_deg<<<(N_EDGES + 255) / 256, 256, 0, stream>>>(dst, deg);
    k_scan<<<1, SCAN_T, 0, stream>>>(deg, rowptr, cursor);
    k_fill<<<(N_EDGES + 255) / 256, 256, 0, stream>>>(src, dst, cursor, csr);

    k_agg1<<<(N_NODES * 64 + 255) / 256, 256, 0, stream>>>(rowptr, csr, x, agg1);

    k_gemm1<<<(N_NODES + NT - 1) / NT, 256, 0, stream>>>(agg1, x, W1l, b1, W1r,
                                                         W2l, W2r, yz);

    k_layer2<<<(N_NODES * 64 + 255) / 256, 256, 0, stream>>>(rowptr, csr, yz, b2, out);
}

// Round 4
// 719.557 us; speedup vs baseline: 2.5719x; 1.3548x over previous
//
#include <hip/hip_runtime.h>

#define N_NODES 100000
#define N_EDGES 1600000
#define IN_C 165
#define HID_C 256
#define OUT_C 2

#define XPAD 168        // bf16 row length (16B-aligned: 21 uint4 chunks)
#define LDSROW 360      // LDS A-tile row stride in shorts (bank-friendly, verified R3-style)

typedef short bf16x8 __attribute__((ext_vector_type(8)));
typedef float f32x4 __attribute__((ext_vector_type(4)));

__device__ inline unsigned short f2bf(float f) {
    unsigned int u = __float_as_uint(f);
    u += 0x7fffu + ((u >> 16) & 1u);
    return (unsigned short)(u >> 16);
}
__device__ inline float bf2f(unsigned short h) {
    return __uint_as_float(((unsigned int)h) << 16);
}

// ---------------------------------------------------------------------------
// Workspace layout (75.78 MB total; R2's 75.2 MB passed, R3's 79.8 MB failed):
//   csr    : ints  [0, 1600000)
//   rowptr : ints  [1600000, 1700001)
//   xb     : bf16  [N][168]   at int offset 1700004      (33.6 MB)
//   aggb   : bf16  [N][168]                              (33.6 MB)
//   Wt     : bf16  [256][352]                            (180 KB)
//   yz     : f32   [N][4]                                (1.6 MB)
//   deg    : ints  OVERLAID on yz[0..100000)   (dead after k_scan)
//   cursor : ints  OVERLAID on yz[100000..200000) (dead after k_fill)
// ---------------------------------------------------------------------------

__global__ void k_deg(const int* __restrict__ dst, int* __restrict__ deg) {
    int e = blockIdx.x * blockDim.x + threadIdx.x;
    if (e < N_EDGES) atomicAdd(&deg[dst[e]], 1);
}

#define SCAN_T 1024
#define SCAN_ITEMS 8
#define SCAN_CHUNK (SCAN_T * SCAN_ITEMS)
__launch_bounds__(SCAN_T)
__global__ void k_scan(const int* __restrict__ deg, int* __restrict__ rowptr,
                       int* __restrict__ cursor) {
    __shared__ int wsums[16];
    __shared__ int wprefix[16];
    const int tid = threadIdx.x;
    const int lane = tid & 63;
    const int wid = tid >> 6;
    int carry = 0;
    if (tid == 0) rowptr[0] = 0;
    for (int base = 0; base < N_NODES; base += SCAN_CHUNK) {
        int idx0 = base + tid * SCAN_ITEMS;
        int l[SCAN_ITEMS];
        int run = 0;
#pragma unroll
        for (int j = 0; j < SCAN_ITEMS; ++j) {
            int idx = idx0 + j;
            int v = (idx < N_NODES) ? deg[idx] : 0;
            run += v;
            l[j] = run;
        }
        int tsum = run;
        int v = tsum;
#pragma unroll
        for (int off = 1; off < 64; off <<= 1) {
            int t = __shfl_up(v, off);
            if (lane >= off) v += t;
        }
        int wv_excl = v - tsum;
        if (lane == 63) wsums[wid] = v;
        __syncthreads();
        if (wid == 0) {
            int s = (lane < 16) ? wsums[lane] : 0;
#pragma unroll
            for (int off = 1; off < 16; off <<= 1) {
                int t = __shfl_up(s, off);
                if (lane >= off) s += t;
            }
            if (lane < 16) wprefix[lane] = s;
        }
        __syncthreads();
        int waveoff = (wid > 0) ? wprefix[wid - 1] : 0;
        int chunk_total = wprefix[15];
        int tbase = carry + waveoff + wv_excl;
#pragma unroll
        for (int j = 0; j < SCAN_ITEMS; ++j) {
            int idx = idx0 + j;
            if (idx < N_NODES) {
                rowptr[idx + 1] = tbase + l[j];
                cursor[idx] = tbase + (j ? l[j - 1] : 0);
            }
        }
        carry += chunk_total;
        __syncthreads();
    }
}

__global__ void k_fill(const int* __restrict__ src, const int* __restrict__ dst,
                       int* __restrict__ cursor, int* __restrict__ csr) {
    int e = blockIdx.x * blockDim.x + threadIdx.x;
    if (e >= N_EDGES) return;
    int d = dst[e];
    int pos = atomicAdd(&cursor[d], 1);
    csr[pos] = src[e];
}

// x fp32 [N][165] -> xb bf16 [N][168] zero-padded
__global__ void k_cvt(const float* __restrict__ x, unsigned short* __restrict__ xb) {
    int idx = blockIdx.x * blockDim.x + threadIdx.x;
    if (idx >= N_NODES * XPAD) return;
    int n = idx / XPAD;
    int k = idx - n * XPAD;
    float v = (k < IN_C) ? x[(size_t)n * IN_C + k] : 0.0f;
    xb[idx] = f2bf(v);
}

// Wt[c][k] = W1l[k][c] (k<165) | W1r[k-168][c] (168<=k<333) | 0, bf16 [256][352]
__global__ void k_wt(const float* __restrict__ W1l, const float* __restrict__ W1r,
                     unsigned short* __restrict__ Wt) {
    int k = blockIdx.x;        // 0..351
    int c = threadIdx.x;       // 0..255
    float v = 0.0f;
    if (k < IN_C) v = W1l[k * HID_C + c];
    else if (k >= XPAD && k < XPAD + IN_C) v = W1r[(k - XPAD) * HID_C + c];
    Wt[(size_t)c * 352 + k] = f2bf(v);
}

// one wave per node: bf16 gather-mean into aggb [N][168]
__global__ void k_agg1b(const int* __restrict__ rowptr, const int* __restrict__ csr,
                        const unsigned short* __restrict__ xb,
                        unsigned short* __restrict__ aggb) {
    int n = (blockIdx.x * blockDim.x + threadIdx.x) >> 6;
    if (n >= N_NODES) return;
    const int lane = threadIdx.x & 63;
    int beg = rowptr[n], end = rowptr[n + 1];
    float a0 = 0.f, a1 = 0.f, a2 = 0.f;
    for (int i = beg; i < end; ++i) {
        const unsigned short* xr = xb + (size_t)csr[i] * XPAD;
        a0 += bf2f(xr[lane]);
        a1 += bf2f(xr[lane + 64]);
        if (lane < XPAD - 128) a2 += bf2f(xr[lane + 128]);
    }
    float invd = 1.0f / fmaxf((float)(end - beg), 1.0f);
    unsigned short* o = aggb + (size_t)n * XPAD;
    o[lane] = f2bf(a0 * invd);
    o[lane + 64] = f2bf(a1 * invd);
    if (lane < XPAD - 128) o[lane + 128] = f2bf(a2 * invd);
}

// MFMA fused GEMM: h = relu([mean|x] @ [W1l;W1r] + b1) (fp32 in regs);
// yz[n] = {h@W2l, h@W2r} via per-lane partial dot + 16-lane reduce + LDS sum.
// block = 256 thr = 4 waves; 64 nodes x 256 cols; wave w owns cols [64w,64w+64)
__launch_bounds__(256)
__global__ void k_gemm1(const unsigned short* __restrict__ aggb,
                        const unsigned short* __restrict__ xb,
                        const unsigned short* __restrict__ Wt,
                        const float* __restrict__ b1,
                        const float* __restrict__ W2l, const float* __restrict__ W2r,
                        float* __restrict__ yz) {
    __shared__ __align__(16) unsigned short lds[64 * LDSROW];   // 45 KB
    const int tid = threadIdx.x;
    const int lane = tid & 63;
    const int w = tid >> 6;
    const int node0 = blockIdx.x * 64;

    // stage A tile: row=node, shorts [0,168)=aggb(mean), [168,336)=xb, [336,360)=0
#pragma unroll
    for (int it = 0; it < 12; ++it) {
        int idx = tid + it * 256;
        if (idx < 64 * 45) {
            int row = idx / 45;
            int c = idx - row * 45;
            int n = node0 + row;
            uint4 v = make_uint4(0, 0, 0, 0);
            if (n < N_NODES) {
                if (c < 21)      v = *(const uint4*)&aggb[(size_t)n * XPAD + c * 8];
                else if (c < 42) v = *(const uint4*)&xb[(size_t)n * XPAD + (c - 21) * 8];
            }
            *(uint4*)&lds[row * LDSROW + c * 8] = v;
        }
    }
    __syncthreads();

    const int arow = lane & 15;       // A row / B col / C col within 16
    const int kgrp = lane >> 4;       // k group
    const int colbase = w * 64;
    f32x4 acc[4][4] = {};

    for (int ks = 0; ks < 11; ++ks) {
        const int k0 = ks * 32 + kgrp * 8;
        bf16x8 bfr[4], afr[4];
#pragma unroll
        for (int n = 0; n < 4; ++n)
            bfr[n] = *(const bf16x8*)&Wt[(size_t)(colbase + n * 16 + arow) * 352 + k0];
#pragma unroll
        for (int m = 0; m < 4; ++m)
            afr[m] = *(const bf16x8*)&lds[(m * 16 + arow) * LDSROW + k0];
#pragma unroll
        for (int m = 0; m < 4; ++m)
#pragma unroll
            for (int n = 0; n < 4; ++n)
                acc[m][n] = __builtin_amdgcn_mfma_f32_16x16x32_bf16(afr[m], bfr[n],
                                                                    acc[m][n], 0, 0, 0);
    }

    // ---- fp32 epilogue: per-lane partial y/z over its 4 cols, reduce 16 lanes ----
    float b1c[4];
    float2 wl[4], wr[4];
#pragma unroll
    for (int n = 0; n < 4; ++n) {
        int c = colbase + n * 16 + arow;
        b1c[n] = b1[c];
        wl[n] = *(const float2*)&W2l[c * 2];
        wr[n] = *(const float2*)&W2r[c * 2];
    }
    __syncthreads();                 // all waves done reading A-tile
    float* part = (float*)lds;       // part[w][row][4] : 4*64*4 floats = 4 KB

#pragma unroll
    for (int m = 0; m < 4; ++m)
#pragma unroll
        for (int r = 0; r < 4; ++r) {
            float y0 = 0.f, y1 = 0.f, z0 = 0.f, z1 = 0.f;
#pragma unroll
            for (int n = 0; n < 4; ++n) {
                float h = fmaxf(acc[m][n][r] + b1c[n], 0.0f);
                y0 = fmaf(h, wl[n].x, y0); y1 = fmaf(h, wl[n].y, y1);
                z0 = fmaf(h, wr[n].x, z0); z1 = fmaf(h, wr[n].y, z1);
            }
#pragma unroll
            for (int off = 1; off < 16; off <<= 1) {
                y0 += __shfl_xor(y0, off); y1 += __shfl_xor(y1, off);
                z0 += __shfl_xor(z0, off); z1 += __shfl_xor(z1, off);
            }
            if (arow == 0) {
                int row = m * 16 + kgrp * 4 + r;
                float* p = &part[(w * 64 + row) * 4];
                p[0] = y0; p[1] = y1; p[2] = z0; p[3] = z1;
            }
        }
    __syncthreads();

    // cross-wave sum: 256 threads = 64 rows x 4 channels
    {
        int row = tid >> 2;
        int ch = tid & 3;
        float s = part[row * 4 + ch] + part[(256 + row * 4) + ch] +
                  part[(512 + row * 4) + ch] + part[(768 + row * 4) + ch];
        int node = node0 + row;
        if (node < N_NODES) yz[(size_t)node * 4 + ch] = s;
    }
}

// one wave per node: out = mean(y[neighbors]) + b2 + z[node]
__global__ void k_layer2(const int* __restrict__ rowptr, const int* __restrict__ csr,
                         const float* __restrict__ yz, const float* __restrict__ b2,
                         float* __restrict__ out) {
    int n = (blockIdx.x * blockDim.x + threadIdx.x) >> 6;
    if (n >= N_NODES) return;
    const int lane = threadIdx.x & 63;
    int beg = rowptr[n], end = rowptr[n + 1];
    float y0 = 0.f, y1 = 0.f;
    for (int i = beg + lane; i < end; i += 64) {
        int s = csr[i];
        float2 v = *(const float2*)&yz[(size_t)s * 4];
        y0 += v.x; y1 += v.y;
    }
#pragma unroll
    for (int off = 32; off >= 1; off >>= 1) {
        y0 += __shfl_xor(y0, off);
        y1 += __shfl_xor(y1, off);
    }
    if (lane == 0) {
        float invd = 1.0f / fmaxf((float)(end - beg), 1.0f);
        float2 o;
        o.x = y0 * invd + b2[0] + yz[(size_t)n * 4 + 2];
        o.y = y1 * invd + b2[1] + yz[(size_t)n * 4 + 3];
        *(float2*)&out[n * 2] = o;
    }
}

extern "C" void kernel_launch(void* const* d_in, const int* in_sizes, int n_in,
                              void* d_out, int out_size, void* d_ws, size_t ws_size,
                              hipStream_t stream) {
    const float* x   = (const float*)d_in[0];
    const int*   ei  = (const int*)d_in[1];
    const int*   src = ei;
    const int*   dst = ei + N_EDGES;
    const float* W1l = (const float*)d_in[2];
    const float* b1  = (const float*)d_in[3];
    const float* W1r = (const float*)d_in[4];
    const float* W2l = (const float*)d_in[5];
    const float* b2  = (const float*)d_in[6];
    const float* W2r = (const float*)d_in[7];
    float* out = (float*)d_out;

    int* wsi = (int*)d_ws;
    int* csr    = wsi;                                   // 1.6M ints
    int* rowptr = wsi + 1600000;                         // 100001 ints
    unsigned short* xb   = (unsigned short*)(wsi + 1700004);
    unsigned short* aggb = xb + (size_t)N_NODES * XPAD;
    unsigned short* Wt   = aggb + (size_t)N_NODES * XPAD;
    float* yz            = (float*)(Wt + 256 * 352);
    // overlays (dead before k_gemm1 writes yz):
    int* deg    = (int*)yz;
    int* cursor = (int*)yz + N_NODES;

    hipMemsetAsync(deg, 0, N_NODES * sizeof(int), stream);

    k_cvt<<<(N_NODES * XPAD + 255) / 256, 256, 0, stream>>>(x, xb);
    k_wt<<<352, 256, 0, stream>>>(W1l, W1r, Wt);
    k_deg<<<(N_EDGES + 255) / 256, 256, 0, stream>>>(dst, deg);
    k_scan<<<1, SCAN_T, 0, stream>>>(deg, rowptr, cursor);
    k_fill<<<(N_EDGES + 255) / 256, 256, 0, stream>>>(src, dst, cursor, csr);
    k_agg1b<<<(N_NODES * 64 + 255) / 256, 256, 0, stream>>>(rowptr, csr, xb, aggb);
    k_gemm1<<<(N_NODES + 63) / 64, 256, 0, stream>>>(aggb, xb, Wt, b1, W2l, W2r, yz);
    k_layer2<<<(N_NODES * 64 + 255) / 256, 256, 0, stream>>>(rowptr, csr, yz, b2, out);
}

// Round 5
// 625.113 us; speedup vs baseline: 2.9604x; 1.1511x over previous
//
#include <hip/hip_runtime.h>

#define N_NODES 100000
#define N_EDGES 1600000
#define IN_C 165
#define HID_C 256
#define OUT_C 2

#define XPAD 168        // bf16 row length (16B-aligned: 21 uint4 / 42 uint2 chunks)
#define LDSROW 360      // LDS A-tile row stride in shorts

typedef short bf16x8 __attribute__((ext_vector_type(8)));
typedef float f32x4 __attribute__((ext_vector_type(4)));

__device__ inline unsigned short f2bf(float f) {
    unsigned int u = __float_as_uint(f);
    u += 0x7fffu + ((u >> 16) & 1u);
    return (unsigned short)(u >> 16);
}
__device__ inline float bf2f(unsigned short h) {
    return __uint_as_float(((unsigned int)h) << 16);
}
__device__ inline unsigned int pack2bf(float a, float b) {
    return (unsigned int)f2bf(a) | ((unsigned int)f2bf(b) << 16);
}

// ---------------------------------------------------------------------------
// Workspace layout (75.78 MB total — identical to R4, which passed):
//   csr    : ints  [0, 1600000)
//   rowptr : ints  [1600000, 1700001)
//   xb     : bf16  [N][168]   at int offset 1700004      (33.6 MB)
//   aggb   : bf16  [N][168]                              (33.6 MB)
//   Wt     : bf16  [256][352]                            (180 KB)
//   yz     : f32   [N][4]                                (1.6 MB)
//   deg    : ints  OVERLAID on yz[0..100000)   (dead after k_scan)
//   cursor : ints  OVERLAID on yz[100000..200000) (dead after k_fill)
// ---------------------------------------------------------------------------

#define SCAN_T 1024
#define SCAN_ITEMS 8
#define SCAN_CHUNK (SCAN_T * SCAN_ITEMS)
__launch_bounds__(SCAN_T)
__global__ void k_scan(const int* __restrict__ deg, int* __restrict__ rowptr,
                       int* __restrict__ cursor) {
    __shared__ int wsums[16];
    __shared__ int wprefix[16];
    const int tid = threadIdx.x;
    const int lane = tid & 63;
    const int wid = tid >> 6;
    int carry = 0;
    if (tid == 0) rowptr[0] = 0;
    for (int base = 0; base < N_NODES; base += SCAN_CHUNK) {
        int idx0 = base + tid * SCAN_ITEMS;
        int l[SCAN_ITEMS];
        int run = 0;
#pragma unroll
        for (int j = 0; j < SCAN_ITEMS; ++j) {
            int idx = idx0 + j;
            int v = (idx < N_NODES) ? deg[idx] : 0;
            run += v;
            l[j] = run;
        }
        int tsum = run;
        int v = tsum;
#pragma unroll
        for (int off = 1; off < 64; off <<= 1) {
            int t = __shfl_up(v, off);
            if (lane >= off) v += t;
        }
        int wv_excl = v - tsum;
        if (lane == 63) wsums[wid] = v;
        __syncthreads();
        if (wid == 0) {
            int s = (lane < 16) ? wsums[lane] : 0;
#pragma unroll
            for (int off = 1; off < 16; off <<= 1) {
                int t = __shfl_up(s, off);
                if (lane >= off) s += t;
            }
            if (lane < 16) wprefix[lane] = s;
        }
        __syncthreads();
        int waveoff = (wid > 0) ? wprefix[wid - 1] : 0;
        int chunk_total = wprefix[15];
        int tbase = carry + waveoff + wv_excl;
#pragma unroll
        for (int j = 0; j < SCAN_ITEMS; ++j) {
            int idx = idx0 + j;
            if (idx < N_NODES) {
                rowptr[idx + 1] = tbase + l[j];
                cursor[idx] = tbase + (j ? l[j - 1] : 0);
            }
        }
        carry += chunk_total;
        __syncthreads();
    }
}

__global__ void k_fill(const int* __restrict__ src, const int* __restrict__ dst,
                       int* __restrict__ cursor, int* __restrict__ csr) {
    int e = blockIdx.x * blockDim.x + threadIdx.x;
    if (e >= N_EDGES) return;
    int d = dst[e];
    int pos = atomicAdd(&cursor[d], 1);
    csr[pos] = src[e];
}

// x fp32 [N][165] -> xb bf16 [N][168] zero-padded (uint2 = 4 ch per thread);
// also folds the degree histogram (idx < N_EDGES).
__global__ void k_cvt(const float* __restrict__ x, const int* __restrict__ dst,
                      uint2* __restrict__ xb2, int* __restrict__ deg) {
    int idx = blockIdx.x * blockDim.x + threadIdx.x;
    if (idx < N_EDGES) atomicAdd(&deg[dst[idx]], 1);
    if (idx >= N_NODES * 42) return;
    int n = idx / 42;
    int t = idx - n * 42;
    int c = 4 * t;
    float f0 = x[(size_t)n * IN_C + c];
    float f1 = (c + 1 < IN_C) ? x[(size_t)n * IN_C + c + 1] : 0.f;
    float f2 = (c + 2 < IN_C) ? x[(size_t)n * IN_C + c + 2] : 0.f;
    float f3 = (c + 3 < IN_C) ? x[(size_t)n * IN_C + c + 3] : 0.f;
    uint2 p;
    p.x = pack2bf(f0, f1);
    p.y = pack2bf(f2, f3);
    xb2[idx] = p;
}

// Wt[c][k] = W1l[k][c] (k<165) | W1r[k-168][c] (168<=k<333) | 0, bf16 [256][352]
__global__ void k_wt(const float* __restrict__ W1l, const float* __restrict__ W1r,
                     unsigned short* __restrict__ Wt) {
    int k = blockIdx.x;        // 0..351
    int c = threadIdx.x;       // 0..255
    float v = 0.0f;
    if (k < IN_C) v = W1l[k * HID_C + c];
    else if (k >= XPAD && k < XPAD + IN_C) v = W1r[(k - XPAD) * HID_C + c];
    Wt[(size_t)c * 352 + k] = f2bf(v);
}

// one wave per node: bf16 gather-mean into aggb [N][168].
// Lane owns channels [4*lane, 4*lane+4) (lanes 0..41); one uint2 load per edge,
// unroll-4 to keep 4 neighbor rows in flight (latency-bound fix).
__global__ void k_agg1b(const int* __restrict__ rowptr, const int* __restrict__ csr,
                        const uint2* __restrict__ xb2, uint2* __restrict__ aggb2) {
    int n = (blockIdx.x * blockDim.x + threadIdx.x) >> 6;
    if (n >= N_NODES) return;
    const int lane = threadIdx.x & 63;
    const bool act = lane < 42;
    int beg = rowptr[n], end = rowptr[n + 1];
    float a0 = 0.f, a1 = 0.f, a2 = 0.f, a3 = 0.f;
    int j = beg;
#define ACC(u) { a0 += bf2f((unsigned short)((u).x & 0xffffu)); \
                 a1 += bf2f((unsigned short)((u).x >> 16)); \
                 a2 += bf2f((unsigned short)((u).y & 0xffffu)); \
                 a3 += bf2f((unsigned short)((u).y >> 16)); }
    for (; j + 3 < end; j += 4) {
        int s0 = csr[j], s1 = csr[j + 1], s2 = csr[j + 2], s3 = csr[j + 3];
        uint2 u0 = make_uint2(0, 0), u1 = make_uint2(0, 0);
        uint2 u2 = make_uint2(0, 0), u3 = make_uint2(0, 0);
        if (act) {
            u0 = xb2[(size_t)s0 * 42 + lane];
            u1 = xb2[(size_t)s1 * 42 + lane];
            u2 = xb2[(size_t)s2 * 42 + lane];
            u3 = xb2[(size_t)s3 * 42 + lane];
        }
        ACC(u0); ACC(u1); ACC(u2); ACC(u3);
    }
    for (; j < end; ++j) {
        int s0 = csr[j];
        uint2 u0 = act ? xb2[(size_t)s0 * 42 + lane] : make_uint2(0, 0);
        ACC(u0);
    }
#undef ACC
    if (act) {
        float invd = 1.0f / fmaxf((float)(end - beg), 1.0f);
        uint2 p;
        p.x = pack2bf(a0 * invd, a1 * invd);
        p.y = pack2bf(a2 * invd, a3 * invd);
        aggb2[(size_t)n * 42 + lane] = p;
    }
}

// MFMA fused GEMM: h = relu([mean|x] @ [W1l;W1r] + b1) (fp32 in regs);
// yz[n] = {h@W2l, h@W2r} via per-lane partial dot + 16-lane reduce + LDS sum.
// block = 256 thr = 4 waves; 64 nodes x 256 cols; wave w owns cols [64w,64w+64)
__launch_bounds__(256)
__global__ void k_gemm1(const unsigned short* __restrict__ aggb,
                        const unsigned short* __restrict__ xb,
                        const unsigned short* __restrict__ Wt,
                        const float* __restrict__ b1,
                        const float* __restrict__ W2l, const float* __restrict__ W2r,
                        float* __restrict__ yz) {
    __shared__ __align__(16) unsigned short lds[64 * LDSROW];   // 45 KB
    const int tid = threadIdx.x;
    const int lane = tid & 63;
    const int w = tid >> 6;
    const int node0 = blockIdx.x * 64;

    // stage A tile: row=node, shorts [0,168)=aggb(mean), [168,336)=xb, [336,360)=0
#pragma unroll
    for (int it = 0; it < 12; ++it) {
        int idx = tid + it * 256;
        if (idx < 64 * 45) {
            int row = idx / 45;
            int c = idx - row * 45;
            int n = node0 + row;
            uint4 v = make_uint4(0, 0, 0, 0);
            if (n < N_NODES) {
                if (c < 21)      v = *(const uint4*)&aggb[(size_t)n * XPAD + c * 8];
                else if (c < 42) v = *(const uint4*)&xb[(size_t)n * XPAD + (c - 21) * 8];
            }
            *(uint4*)&lds[row * LDSROW + c * 8] = v;
        }
    }
    __syncthreads();

    const int arow = lane & 15;       // A row / B col / C col within 16
    const int kgrp = lane >> 4;       // k group
    const int colbase = w * 64;
    f32x4 acc[4][4] = {};

    for (int ks = 0; ks < 11; ++ks) {
        const int k0 = ks * 32 + kgrp * 8;
        bf16x8 bfr[4], afr[4];
#pragma unroll
        for (int n = 0; n < 4; ++n)
            bfr[n] = *(const bf16x8*)&Wt[(size_t)(colbase + n * 16 + arow) * 352 + k0];
#pragma unroll
        for (int m = 0; m < 4; ++m)
            afr[m] = *(const bf16x8*)&lds[(m * 16 + arow) * LDSROW + k0];
#pragma unroll
        for (int m = 0; m < 4; ++m)
#pragma unroll
            for (int n = 0; n < 4; ++n)
                acc[m][n] = __builtin_amdgcn_mfma_f32_16x16x32_bf16(afr[m], bfr[n],
                                                                    acc[m][n], 0, 0, 0);
    }

    // ---- fp32 epilogue: per-lane partial y/z over its 4 cols, reduce 16 lanes ----
    float b1c[4];
    float2 wl[4], wr[4];
#pragma unroll
    for (int n = 0; n < 4; ++n) {
        int c = colbase + n * 16 + arow;
        b1c[n] = b1[c];
        wl[n] = *(const float2*)&W2l[c * 2];
        wr[n] = *(const float2*)&W2r[c * 2];
    }
    __syncthreads();                 // all waves done reading A-tile
    float* part = (float*)lds;       // part[w][row][4] : 4*64*4 floats = 4 KB

#pragma unroll
    for (int m = 0; m < 4; ++m)
#pragma unroll
        for (int r = 0; r < 4; ++r) {
            float y0 = 0.f, y1 = 0.f, z0 = 0.f, z1 = 0.f;
#pragma unroll
            for (int n = 0; n < 4; ++n) {
                float h = fmaxf(acc[m][n][r] + b1c[n], 0.0f);
                y0 = fmaf(h, wl[n].x, y0); y1 = fmaf(h, wl[n].y, y1);
                z0 = fmaf(h, wr[n].x, z0); z1 = fmaf(h, wr[n].y, z1);
            }
#pragma unroll
            for (int off = 1; off < 16; off <<= 1) {
                y0 += __shfl_xor(y0, off); y1 += __shfl_xor(y1, off);
                z0 += __shfl_xor(z0, off); z1 += __shfl_xor(z1, off);
            }
            if (arow == 0) {
                int row = m * 16 + kgrp * 4 + r;
                float* p = &part[(w * 64 + row) * 4];
                p[0] = y0; p[1] = y1; p[2] = z0; p[3] = z1;
            }
        }
    __syncthreads();

    // cross-wave sum: 256 threads = 64 rows x 4 channels
    {
        int row = tid >> 2;
        int ch = tid & 3;
        float s = part[row * 4 + ch] + part[(256 + row * 4) + ch] +
                  part[(512 + row * 4) + ch] + part[(768 + row * 4) + ch];
        int node = node0 + row;
        if (node < N_NODES) yz[(size_t)node * 4 + ch] = s;
    }
}

// one wave per node: out = mean(y[neighbors]) + b2 + z[node]
__global__ void k_layer2(const int* __restrict__ rowptr, const int* __restrict__ csr,
                         const float* __restrict__ yz, const float* __restrict__ b2,
                         float* __restrict__ out) {
    int n = (blockIdx.x * blockDim.x + threadIdx.x) >> 6;
    if (n >= N_NODES) return;
    const int lane = threadIdx.x & 63;
    int beg = rowptr[n], end = rowptr[n + 1];
    float y0 = 0.f, y1 = 0.f;
    for (int i = beg + lane; i < end; i += 64) {
        int s = csr[i];
        float2 v = *(const float2*)&yz[(size_t)s * 4];
        y0 += v.x; y1 += v.y;
    }
#pragma unroll
    for (int off = 32; off >= 1; off >>= 1) {
        y0 += __shfl_xor(y0, off);
        y1 += __shfl_xor(y1, off);
    }
    if (lane == 0) {
        float invd = 1.0f / fmaxf((float)(end - beg), 1.0f);
        float2 o;
        o.x = y0 * invd + b2[0] + yz[(size_t)n * 4 + 2];
        o.y = y1 * invd + b2[1] + yz[(size_t)n * 4 + 3];
        *(float2*)&out[n * 2] = o;
    }
}

extern "C" void kernel_launch(void* const* d_in, const int* in_sizes, int n_in,
                              void* d_out, int out_size, void* d_ws, size_t ws_size,
                              hipStream_t stream) {
    const float* x   = (const float*)d_in[0];
    const int*   ei  = (const int*)d_in[1];
    const int*   src = ei;
    const int*   dst = ei + N_EDGES;
    const float* W1l = (const float*)d_in[2];
    const float* b1  = (const float*)d_in[3];
    const float* W1r = (const float*)d_in[4];
    const float* W2l = (const float*)d_in[5];
    const float* b2  = (const float*)d_in[6];
    const float* W2r = (const float*)d_in[7];
    float* out = (float*)d_out;

    int* wsi = (int*)d_ws;
    int* csr    = wsi;                                   // 1.6M ints
    int* rowptr = wsi + 1600000;                         // 100001 ints
    unsigned short* xb   = (unsigned short*)(wsi + 1700004);
    unsigned short* aggb = xb + (size_t)N_NODES * XPAD;
    unsigned short* Wt   = aggb + (size_t)N_NODES * XPAD;
    float* yz            = (float*)(Wt + 256 * 352);
    // overlays (dead before k_gemm1 writes yz):
    int* deg    = (int*)yz;
    int* cursor = (int*)yz + N_NODES;

    hipMemsetAsync(deg, 0, N_NODES * sizeof(int), stream);

    k_cvt<<<(N_NODES * 42 + 255) / 256, 256, 0, stream>>>(x, dst, (uint2*)xb, deg);
    k_wt<<<352, 256, 0, stream>>>(W1l, W1r, Wt);
    k_scan<<<1, SCAN_T, 0, stream>>>(deg, rowptr, cursor);
    k_fill<<<(N_EDGES + 255) / 256, 256, 0, stream>>>(src, dst, cursor, csr);
    k_agg1b<<<(N_NODES * 64 + 255) / 256, 256, 0, stream>>>(rowptr, csr,
                                                            (const uint2*)xb,
                                                            (uint2*)aggb);
    k_gemm1<<<(N_NODES + 63) / 64, 256, 0, stream>>>(aggb, xb, Wt, b1, W2l, W2r, yz);
    k_layer2<<<(N_NODES * 64 + 255) / 256, 256, 0, stream>>>(rowptr, csr, yz, b2, out);
}

// Round 6
// 492.846 us; speedup vs baseline: 3.7549x; 1.2684x over previous
//
#include <hip/hip_runtime.h>

#define N_NODES 100000
#define N_EDGES 1600000
#define IN_C 165
#define HID_C 256
#define OUT_C 2

#define XPAD 168        // bf16 row length (16B-aligned: 21 uint4 / 42 uint2 chunks)
#define LDSROW 360      // LDS A-tile row stride in shorts
#define NBLK_SCAN 98    // ceil(100000/1024)

typedef short bf16x8 __attribute__((ext_vector_type(8)));
typedef float f32x4 __attribute__((ext_vector_type(4)));

__device__ inline unsigned short f2bf(float f) {
    unsigned int u = __float_as_uint(f);
    u += 0x7fffu + ((u >> 16) & 1u);
    return (unsigned short)(u >> 16);
}
__device__ inline float bf2f(unsigned short h) {
    return __uint_as_float(((unsigned int)h) << 16);
}
__device__ inline unsigned int pack2bf(float a, float b) {
    return (unsigned int)f2bf(a) | ((unsigned int)f2bf(b) << 16);
}

// ---------------------------------------------------------------------------
// Workspace layout (75.78 MB total — identical envelope to R4/R5, which passed):
//   csr    : ints  [0, 1600000)
//   rowptr : ints  [1600000, 1700001)
//   xb     : bf16  [N][168]   at int offset 1700004      (33.6 MB)
//   aggb   : bf16  [N][168]                              (33.6 MB)
//   Wt     : bf16  [256][352]                            (180 KB)
//   yz     : f32   [N][4]                                (1.6 MB)
// overlays on yz (all dead before k_gemm1 writes yz):
//   deg         : ints yz[0..100000)
//   incl/cursor : ints yz[100000..200000)   (scan1 incl -> scan3 rewrites as cursor)
//   btot        : ints yz[200000..200098)
// ---------------------------------------------------------------------------

// ---- parallel 3-pass scan ----
__launch_bounds__(1024)
__global__ void k_scan1(const int* __restrict__ deg, int* __restrict__ incl,
                        int* __restrict__ btot) {
    const int tid = threadIdx.x;
    const int idx = blockIdx.x * 1024 + tid;
    const int lane = tid & 63, wid = tid >> 6;
    __shared__ int ws[16];
    int v = (idx < N_NODES) ? deg[idx] : 0;
    int s = v;
#pragma unroll
    for (int off = 1; off < 64; off <<= 1) {
        int t = __shfl_up(s, off);
        if (lane >= off) s += t;
    }
    if (lane == 63) ws[wid] = s;
    __syncthreads();
    if (wid == 0) {
        int p = (lane < 16) ? ws[lane] : 0;
#pragma unroll
        for (int off = 1; off < 16; off <<= 1) {
            int t = __shfl_up(p, off);
            if (lane >= off) p += t;
        }
        if (lane < 16) ws[lane] = p;
    }
    __syncthreads();
    int blockincl = s + (wid > 0 ? ws[wid - 1] : 0);
    if (idx < N_NODES) incl[idx] = blockincl;
    if (tid == 1023) btot[blockIdx.x] = blockincl;   // block grand total
}

__global__ void k_scan2(int* __restrict__ btot) {   // 1 block, 64 threads
    const int lane = threadIdx.x;
    int a = (2 * lane < NBLK_SCAN) ? btot[2 * lane] : 0;
    int b = (2 * lane + 1 < NBLK_SCAN) ? btot[2 * lane + 1] : 0;
    int p = a + b;
#pragma unroll
    for (int off = 1; off < 64; off <<= 1) {
        int t = __shfl_up(p, off);
        if (lane >= off) p += t;
    }
    if (2 * lane < NBLK_SCAN) btot[2 * lane] = p - b;
    if (2 * lane + 1 < NBLK_SCAN) btot[2 * lane + 1] = p;
}

__launch_bounds__(1024)
__global__ void k_scan3(const int* __restrict__ deg, int* incl_cursor,
                        const int* __restrict__ btot, int* __restrict__ rowptr) {
    const int idx = blockIdx.x * 1024 + threadIdx.x;
    if (idx == 0) rowptr[0] = 0;
    if (idx >= N_NODES) return;
    int off = (blockIdx.x > 0) ? btot[blockIdx.x - 1] : 0;
    int v = incl_cursor[idx] + off;      // inclusive prefix
    rowptr[idx + 1] = v;
    incl_cursor[idx] = v - deg[idx];     // exclusive prefix = fill cursor
}

__global__ void k_fill(const int* __restrict__ src, const int* __restrict__ dst,
                       int* __restrict__ cursor, int* __restrict__ csr) {
    int e = blockIdx.x * blockDim.x + threadIdx.x;
    if (e >= N_EDGES) return;
    int d = dst[e];
    int pos = atomicAdd(&cursor[d], 1);
    csr[pos] = src[e];
}

// x fp32 [N][165] -> xb bf16 [N][168] zero-padded (uint2 = 4 ch per thread);
// also folds the degree histogram (idx < N_EDGES).
__global__ void k_cvt(const float* __restrict__ x, const int* __restrict__ dst,
                      uint2* __restrict__ xb2, int* __restrict__ deg) {
    int idx = blockIdx.x * blockDim.x + threadIdx.x;
    if (idx < N_EDGES) atomicAdd(&deg[dst[idx]], 1);
    if (idx >= N_NODES * 42) return;
    int n = idx / 42;
    int t = idx - n * 42;
    int c = 4 * t;
    float f0 = x[(size_t)n * IN_C + c];
    float f1 = (c + 1 < IN_C) ? x[(size_t)n * IN_C + c + 1] : 0.f;
    float f2 = (c + 2 < IN_C) ? x[(size_t)n * IN_C + c + 2] : 0.f;
    float f3 = (c + 3 < IN_C) ? x[(size_t)n * IN_C + c + 3] : 0.f;
    uint2 p;
    p.x = pack2bf(f0, f1);
    p.y = pack2bf(f2, f3);
    xb2[idx] = p;
}

// Wt[c][k] = W1l[k][c] (k<165) | W1r[k-168][c] (168<=k<333) | 0, bf16 [256][352]
__global__ void k_wt(const float* __restrict__ W1l, const float* __restrict__ W1r,
                     unsigned short* __restrict__ Wt) {
    int k = blockIdx.x;        // 0..351
    int c = threadIdx.x;       // 0..255
    float v = 0.0f;
    if (k < IN_C) v = W1l[k * HID_C + c];
    else if (k >= XPAD && k < XPAD + IN_C) v = W1r[(k - XPAD) * HID_C + c];
    Wt[(size_t)c * 352 + k] = f2bf(v);
}

// one wave per node: bf16 gather-mean into aggb [N][168].
// Lane owns channels [4*lane, 4*lane+4) (lanes 0..41); one uint2 load per edge,
// unroll-4 to keep 4 neighbor rows in flight (latency-bound fix).
__global__ void k_agg1b(const int* __restrict__ rowptr, const int* __restrict__ csr,
                        const uint2* __restrict__ xb2, uint2* __restrict__ aggb2) {
    int n = (blockIdx.x * blockDim.x + threadIdx.x) >> 6;
    if (n >= N_NODES) return;
    const int lane = threadIdx.x & 63;
    const bool act = lane < 42;
    int beg = rowptr[n], end = rowptr[n + 1];
    float a0 = 0.f, a1 = 0.f, a2 = 0.f, a3 = 0.f;
    int j = beg;
#define ACC(u) { a0 += bf2f((unsigned short)((u).x & 0xffffu)); \
                 a1 += bf2f((unsigned short)((u).x >> 16)); \
                 a2 += bf2f((unsigned short)((u).y & 0xffffu)); \
                 a3 += bf2f((unsigned short)((u).y >> 16)); }
    for (; j + 3 < end; j += 4) {
        int s0 = csr[j], s1 = csr[j + 1], s2 = csr[j + 2], s3 = csr[j + 3];
        uint2 u0 = make_uint2(0, 0), u1 = make_uint2(0, 0);
        uint2 u2 = make_uint2(0, 0), u3 = make_uint2(0, 0);
        if (act) {
            u0 = xb2[(size_t)s0 * 42 + lane];
            u1 = xb2[(size_t)s1 * 42 + lane];
            u2 = xb2[(size_t)s2 * 42 + lane];
            u3 = xb2[(size_t)s3 * 42 + lane];
        }
        ACC(u0); ACC(u1); ACC(u2); ACC(u3);
    }
    for (; j < end; ++j) {
        int s0 = csr[j];
        uint2 u0 = act ? xb2[(size_t)s0 * 42 + lane] : make_uint2(0, 0);
        ACC(u0);
    }
#undef ACC
    if (act) {
        float invd = 1.0f / fmaxf((float)(end - beg), 1.0f);
        uint2 p;
        p.x = pack2bf(a0 * invd, a1 * invd);
        p.y = pack2bf(a2 * invd, a3 * invd);
        aggb2[(size_t)n * 42 + lane] = p;
    }
}

// MFMA fused GEMM: h = relu([mean|x] @ [W1l;W1r] + b1) (fp32 in regs);
// yz[n] = {h@W2l, h@W2r} via per-lane partial dot + 16-lane reduce + LDS sum.
// block = 256 thr = 4 waves; 64 nodes x 256 cols; wave w owns cols [64w,64w+64)
__launch_bounds__(256)
__global__ void k_gemm1(const unsigned short* __restrict__ aggb,
                        const unsigned short* __restrict__ xb,
                        const unsigned short* __restrict__ Wt,
                        const float* __restrict__ b1,
                        const float* __restrict__ W2l, const float* __restrict__ W2r,
                        float* __restrict__ yz) {
    __shared__ __align__(16) unsigned short lds[64 * LDSROW];   // 45 KB
    const int tid = threadIdx.x;
    const int lane = tid & 63;
    const int w = tid >> 6;
    const int node0 = blockIdx.x * 64;

    // stage A tile: row=node, shorts [0,168)=aggb(mean), [168,336)=xb, [336,360)=0
#pragma unroll
    for (int it = 0; it < 12; ++it) {
        int idx = tid + it * 256;
        if (idx < 64 * 45) {
            int row = idx / 45;
            int c = idx - row * 45;
            int n = node0 + row;
            uint4 v = make_uint4(0, 0, 0, 0);
            if (n < N_NODES) {
                if (c < 21)      v = *(const uint4*)&aggb[(size_t)n * XPAD + c * 8];
                else if (c < 42) v = *(const uint4*)&xb[(size_t)n * XPAD + (c - 21) * 8];
            }
            *(uint4*)&lds[row * LDSROW + c * 8] = v;
        }
    }
    __syncthreads();

    const int arow = lane & 15;       // A row / B col / C col within 16
    const int kgrp = lane >> 4;       // k group
    const int colbase = w * 64;
    f32x4 acc[4][4] = {};

    for (int ks = 0; ks < 11; ++ks) {
        const int k0 = ks * 32 + kgrp * 8;
        bf16x8 bfr[4], afr[4];
#pragma unroll
        for (int n = 0; n < 4; ++n)
            bfr[n] = *(const bf16x8*)&Wt[(size_t)(colbase + n * 16 + arow) * 352 + k0];
#pragma unroll
        for (int m = 0; m < 4; ++m)
            afr[m] = *(const bf16x8*)&lds[(m * 16 + arow) * LDSROW + k0];
#pragma unroll
        for (int m = 0; m < 4; ++m)
#pragma unroll
            for (int n = 0; n < 4; ++n)
                acc[m][n] = __builtin_amdgcn_mfma_f32_16x16x32_bf16(afr[m], bfr[n],
                                                                    acc[m][n], 0, 0, 0);
    }

    // ---- fp32 epilogue: per-lane partial y/z over its 4 cols, reduce 16 lanes ----
    float b1c[4];
    float2 wl[4], wr[4];
#pragma unroll
    for (int n = 0; n < 4; ++n) {
        int c = colbase + n * 16 + arow;
        b1c[n] = b1[c];
        wl[n] = *(const float2*)&W2l[c * 2];
        wr[n] = *(const float2*)&W2r[c * 2];
    }
    __syncthreads();                 // all waves done reading A-tile
    float* part = (float*)lds;       // part[w][row][4] : 4*64*4 floats = 4 KB

#pragma unroll
    for (int m = 0; m < 4; ++m)
#pragma unroll
        for (int r = 0; r < 4; ++r) {
            float y0 = 0.f, y1 = 0.f, z0 = 0.f, z1 = 0.f;
#pragma unroll
            for (int n = 0; n < 4; ++n) {
                float h = fmaxf(acc[m][n][r] + b1c[n], 0.0f);
                y0 = fmaf(h, wl[n].x, y0); y1 = fmaf(h, wl[n].y, y1);
                z0 = fmaf(h, wr[n].x, z0); z1 = fmaf(h, wr[n].y, z1);
            }
#pragma unroll
            for (int off = 1; off < 16; off <<= 1) {
                y0 += __shfl_xor(y0, off); y1 += __shfl_xor(y1, off);
                z0 += __shfl_xor(z0, off); z1 += __shfl_xor(z1, off);
            }
            if (arow == 0) {
                int row = m * 16 + kgrp * 4 + r;
                float* p = &part[(w * 64 + row) * 4];
                p[0] = y0; p[1] = y1; p[2] = z0; p[3] = z1;
            }
        }
    __syncthreads();

    // cross-wave sum: 256 threads = 64 rows x 4 channels
    {
        int row = tid >> 2;
        int ch = tid & 3;
        float s = part[row * 4 + ch] + part[(256 + row * 4) + ch] +
                  part[(512 + row * 4) + ch] + part[(768 + row * 4) + ch];
        int node = node0 + row;
        if (node < N_NODES) yz[(size_t)node * 4 + ch] = s;
    }
}

// one wave per node: out = mean(y[neighbors]) + b2 + z[node]
__global__ void k_layer2(const int* __restrict__ rowptr, const int* __restrict__ csr,
                         const float* __restrict__ yz, const float* __restrict__ b2,
                         float* __restrict__ out) {
    int n = (blockIdx.x * blockDim.x + threadIdx.x) >> 6;
    if (n >= N_NODES) return;
    const int lane = threadIdx.x & 63;
    int beg = rowptr[n], end = rowptr[n + 1];
    float y0 = 0.f, y1 = 0.f;
    for (int i = beg + lane; i < end; i += 64) {
        int s = csr[i];
        float2 v = *(const float2*)&yz[(size_t)s * 4];
        y0 += v.x; y1 += v.y;
    }
#pragma unroll
    for (int off = 32; off >= 1; off >>= 1) {
        y0 += __shfl_xor(y0, off);
        y1 += __shfl_xor(y1, off);
    }
    if (lane == 0) {
        float invd = 1.0f / fmaxf((float)(end - beg), 1.0f);
        float2 o;
        o.x = y0 * invd + b2[0] + yz[(size_t)n * 4 + 2];
        o.y = y1 * invd + b2[1] + yz[(size_t)n * 4 + 3];
        *(float2*)&out[n * 2] = o;
    }
}

extern "C" void kernel_launch(void* const* d_in, const int* in_sizes, int n_in,
                              void* d_out, int out_size, void* d_ws, size_t ws_size,
                              hipStream_t stream) {
    const float* x   = (const float*)d_in[0];
    const int*   ei  = (const int*)d_in[1];
    const int*   src = ei;
    const int*   dst = ei + N_EDGES;
    const float* W1l = (const float*)d_in[2];
    const float* b1  = (const float*)d_in[3];
    const float* W1r = (const float*)d_in[4];
    const float* W2l = (const float*)d_in[5];
    const float* b2  = (const float*)d_in[6];
    const float* W2r = (const float*)d_in[7];
    float* out = (float*)d_out;

    int* wsi = (int*)d_ws;
    int* csr    = wsi;                                   // 1.6M ints
    int* rowptr = wsi + 1600000;                         // 100001 ints
    unsigned short* xb   = (unsigned short*)(wsi + 1700004);
    unsigned short* aggb = xb + (size_t)N_NODES * XPAD;
    unsigned short* Wt   = aggb + (size_t)N_NODES * XPAD;
    float* yz            = (float*)(Wt + 256 * 352);
    // overlays (dead before k_gemm1 writes yz):
    int* deg    = (int*)yz;
    int* inccur = (int*)yz + N_NODES;    // scan1 incl -> scan3 cursor
    int* btot   = (int*)yz + 2 * N_NODES;

    hipMemsetAsync(deg, 0, N_NODES * sizeof(int), stream);

    k_cvt<<<(N_NODES * 42 + 255) / 256, 256, 0, stream>>>(x, dst, (uint2*)xb, deg);
    k_wt<<<352, 256, 0, stream>>>(W1l, W1r, Wt);
    k_scan1<<<NBLK_SCAN, 1024, 0, stream>>>(deg, inccur, btot);
    k_scan2<<<1, 64, 0, stream>>>(btot);
    k_scan3<<<NBLK_SCAN, 1024, 0, stream>>>(deg, inccur, btot, rowptr);
    k_fill<<<(N_EDGES + 255) / 256, 256, 0, stream>>>(src, dst, inccur, csr);
    k_agg1b<<<(N_NODES * 64 + 255) / 256, 256, 0, stream>>>(rowptr, csr,
                                                            (const uint2*)xb,
                                                            (uint2*)aggb);
    k_gemm1<<<(N_NODES + 63) / 64, 256, 0, stream>>>(aggb, xb, Wt, b1, W2l, W2r, yz);
    k_layer2<<<(N_NODES * 64 + 255) / 256, 256, 0, stream>>>(rowptr, csr, yz, b2, out);
}

// Round 7
// 466.268 us; speedup vs baseline: 3.9690x; 1.0570x over previous
//
#include <hip/hip_runtime.h>

#define N_NODES 100000
#define N_EDGES 1600000
#define IN_C 165
#define HID_C 256
#define OUT_C 2

#define XPAD 168        // bf16 row length (16B-aligned: 21 uint4 / 42 uint2 chunks)
#define LDSROW 360      // LDS A-tile row stride in shorts
#define NBLK_SCAN 98    // ceil(100000/1024)

typedef short bf16x8 __attribute__((ext_vector_type(8)));
typedef float f32x4 __attribute__((ext_vector_type(4)));

__device__ inline unsigned short f2bf(float f) {
    unsigned int u = __float_as_uint(f);
    u += 0x7fffu + ((u >> 16) & 1u);
    return (unsigned short)(u >> 16);
}
__device__ inline float bf2f(unsigned short h) {
    return __uint_as_float(((unsigned int)h) << 16);
}
__device__ inline unsigned int pack2bf(float a, float b) {
    return (unsigned int)f2bf(a) | ((unsigned int)f2bf(b) << 16);
}

// ---------------------------------------------------------------------------
// Workspace layout (75.78 MB total — identical envelope to R4-R6, which passed):
//   csr    : ints  [0, 1600000)
//   rowptr : ints  [1600000, 1700001)
//   xb     : bf16  [N][168]   at int offset 1700004      (33.6 MB)
//   aggb   : bf16  [N][168]                              (33.6 MB)
//   Wt     : bf16  [256][352]                            (180 KB)
//   yz     : f32   [N][4]                                (1.6 MB)
// overlays on yz (all dead before k_gemm1 writes yz):
//   deg         : ints yz[0..100000)
//   incl/cursor : ints yz[100000..200000)
//   btot        : ints yz[200000..200098)
// ---------------------------------------------------------------------------

// ---- parallel 3-pass scan ----
__launch_bounds__(1024)
__global__ void k_scan1(const int* __restrict__ deg, int* __restrict__ incl,
                        int* __restrict__ btot) {
    const int tid = threadIdx.x;
    const int idx = blockIdx.x * 1024 + tid;
    const int lane = tid & 63, wid = tid >> 6;
    __shared__ int ws[16];
    int v = (idx < N_NODES) ? deg[idx] : 0;
    int s = v;
#pragma unroll
    for (int off = 1; off < 64; off <<= 1) {
        int t = __shfl_up(s, off);
        if (lane >= off) s += t;
    }
    if (lane == 63) ws[wid] = s;
    __syncthreads();
    if (wid == 0) {
        int p = (lane < 16) ? ws[lane] : 0;
#pragma unroll
        for (int off = 1; off < 16; off <<= 1) {
            int t = __shfl_up(p, off);
            if (lane >= off) p += t;
        }
        if (lane < 16) ws[lane] = p;
    }
    __syncthreads();
    int blockincl = s + (wid > 0 ? ws[wid - 1] : 0);
    if (idx < N_NODES) incl[idx] = blockincl;
    if (tid == 1023) btot[blockIdx.x] = blockincl;   // block grand total
}

__global__ void k_scan2(int* __restrict__ btot) {   // 1 block, 64 threads
    const int lane = threadIdx.x;
    int a = (2 * lane < NBLK_SCAN) ? btot[2 * lane] : 0;
    int b = (2 * lane + 1 < NBLK_SCAN) ? btot[2 * lane + 1] : 0;
    int p = a + b;
#pragma unroll
    for (int off = 1; off < 64; off <<= 1) {
        int t = __shfl_up(p, off);
        if (lane >= off) p += t;
    }
    if (2 * lane < NBLK_SCAN) btot[2 * lane] = p - b;
    if (2 * lane + 1 < NBLK_SCAN) btot[2 * lane + 1] = p;
}

__launch_bounds__(1024)
__global__ void k_scan3(const int* __restrict__ deg, int* incl_cursor,
                        const int* __restrict__ btot, int* __restrict__ rowptr) {
    const int idx = blockIdx.x * 1024 + threadIdx.x;
    if (idx == 0) rowptr[0] = 0;
    if (idx >= N_NODES) return;
    int off = (blockIdx.x > 0) ? btot[blockIdx.x - 1] : 0;
    int v = incl_cursor[idx] + off;      // inclusive prefix
    rowptr[idx + 1] = v;
    incl_cursor[idx] = v - deg[idx];     // exclusive prefix = fill cursor
}

// XCD-partitioned CSR fill: block role = blockIdx&7 owns dst range
// [role*12500, role*12500+12500). Every role scans the whole (L3-resident)
// edge list; csr/cursor lines are then written by a single XCD -> no dirty-line
// ping-pong across XCD L2s (R6: WRITE_SIZE was 105 MB for a 6.4 MB array).
#define FILL_GRID 2048
__global__ void k_fill(const int* __restrict__ src, const int* __restrict__ dst,
                       int* __restrict__ cursor, int* __restrict__ csr) {
    const int role = blockIdx.x & 7;
    const int nchunk = gridDim.x >> 3;
    const int lo = role * (N_NODES / 8);
    const int hi = lo + (N_NODES / 8);
    for (int e = (blockIdx.x >> 3) * 256 + threadIdx.x; e < N_EDGES;
         e += nchunk * 256) {
        int d = dst[e];
        int s = src[e];
        if (d >= lo && d < hi) {
            int pos = atomicAdd(&cursor[d], 1);
            csr[pos] = s;
        }
    }
}

// x fp32 [N][165] -> xb bf16 [N][168] zero-padded (uint2 = 4 ch per thread);
// also folds the degree histogram (idx < N_EDGES).
__global__ void k_cvt(const float* __restrict__ x, const int* __restrict__ dst,
                      uint2* __restrict__ xb2, int* __restrict__ deg) {
    int idx = blockIdx.x * blockDim.x + threadIdx.x;
    if (idx < N_EDGES) atomicAdd(&deg[dst[idx]], 1);
    if (idx >= N_NODES * 42) return;
    int n = idx / 42;
    int t = idx - n * 42;
    int c = 4 * t;
    float f0 = x[(size_t)n * IN_C + c];
    float f1 = (c + 1 < IN_C) ? x[(size_t)n * IN_C + c + 1] : 0.f;
    float f2 = (c + 2 < IN_C) ? x[(size_t)n * IN_C + c + 2] : 0.f;
    float f3 = (c + 3 < IN_C) ? x[(size_t)n * IN_C + c + 3] : 0.f;
    uint2 p;
    p.x = pack2bf(f0, f1);
    p.y = pack2bf(f2, f3);
    xb2[idx] = p;
}

// Wt[c][k] = W1l[k][c] (k<165) | W1r[k-168][c] (168<=k<333) | 0, bf16 [256][352]
__global__ void k_wt(const float* __restrict__ W1l, const float* __restrict__ W1r,
                     unsigned short* __restrict__ Wt) {
    int k = blockIdx.x;        // 0..351
    int c = threadIdx.x;       // 0..255
    float v = 0.0f;
    if (k < IN_C) v = W1l[k * HID_C + c];
    else if (k >= XPAD && k < XPAD + IN_C) v = W1r[(k - XPAD) * HID_C + c];
    Wt[(size_t)c * 352 + k] = f2bf(v);
}

// one wave per node: bf16 gather-mean into aggb [N][168].
// Lane owns channels [4*lane, 4*lane+4) (lanes 0..41); one uint2 load per edge,
// unroll-8 to keep 8 neighbor rows in flight (latency-bound fix).
__global__ void k_agg1b(const int* __restrict__ rowptr, const int* __restrict__ csr,
                        const uint2* __restrict__ xb2, uint2* __restrict__ aggb2) {
    int n = (blockIdx.x * blockDim.x + threadIdx.x) >> 6;
    if (n >= N_NODES) return;
    const int lane = threadIdx.x & 63;
    const bool act = lane < 42;
    int beg = rowptr[n], end = rowptr[n + 1];
    float a0 = 0.f, a1 = 0.f, a2 = 0.f, a3 = 0.f;
    int j = beg;
#define ACC(u) { a0 += bf2f((unsigned short)((u).x & 0xffffu)); \
                 a1 += bf2f((unsigned short)((u).x >> 16)); \
                 a2 += bf2f((unsigned short)((u).y & 0xffffu)); \
                 a3 += bf2f((unsigned short)((u).y >> 16)); }
    for (; j + 7 < end; j += 8) {
        uint2 u[8];
#pragma unroll
        for (int q = 0; q < 8; ++q) {
            int s = csr[j + q];
            u[q] = act ? xb2[(size_t)s * 42 + lane] : make_uint2(0, 0);
        }
#pragma unroll
        for (int q = 0; q < 8; ++q) ACC(u[q]);
    }
    for (; j + 3 < end; j += 4) {
        uint2 u[4];
#pragma unroll
        for (int q = 0; q < 4; ++q) {
            int s = csr[j + q];
            u[q] = act ? xb2[(size_t)s * 42 + lane] : make_uint2(0, 0);
        }
#pragma unroll
        for (int q = 0; q < 4; ++q) ACC(u[q]);
    }
    for (; j < end; ++j) {
        int s0 = csr[j];
        uint2 u0 = act ? xb2[(size_t)s0 * 42 + lane] : make_uint2(0, 0);
        ACC(u0);
    }
#undef ACC
    if (act) {
        float invd = 1.0f / fmaxf((float)(end - beg), 1.0f);
        uint2 p;
        p.x = pack2bf(a0 * invd, a1 * invd);
        p.y = pack2bf(a2 * invd, a3 * invd);
        aggb2[(size_t)n * 42 + lane] = p;
    }
}

// MFMA fused GEMM: h = relu([mean|x] @ [W1l;W1r] + b1) (fp32 in regs);
// yz[n] = {h@W2l, h@W2r} via per-lane partial dot + 16-lane reduce + LDS sum.
// block = 256 thr = 4 waves; 64 nodes x 256 cols; wave w owns cols [64w,64w+64)
__launch_bounds__(256)
__global__ void k_gemm1(const unsigned short* __restrict__ aggb,
                        const unsigned short* __restrict__ xb,
                        const unsigned short* __restrict__ Wt,
                        const float* __restrict__ b1,
                        const float* __restrict__ W2l, const float* __restrict__ W2r,
                        float* __restrict__ yz) {
    __shared__ __align__(16) unsigned short lds[64 * LDSROW];   // 45 KB
    const int tid = threadIdx.x;
    const int lane = tid & 63;
    const int w = tid >> 6;
    const int node0 = blockIdx.x * 64;

    // stage A tile: row=node, shorts [0,168)=aggb(mean), [168,336)=xb, [336,360)=0
#pragma unroll
    for (int it = 0; it < 12; ++it) {
        int idx = tid + it * 256;
        if (idx < 64 * 45) {
            int row = idx / 45;
            int c = idx - row * 45;
            int n = node0 + row;
            uint4 v = make_uint4(0, 0, 0, 0);
            if (n < N_NODES) {
                if (c < 21)      v = *(const uint4*)&aggb[(size_t)n * XPAD + c * 8];
                else if (c < 42) v = *(const uint4*)&xb[(size_t)n * XPAD + (c - 21) * 8];
            }
            *(uint4*)&lds[row * LDSROW + c * 8] = v;
        }
    }
    __syncthreads();

    const int arow = lane & 15;       // A row / B col / C col within 16
    const int kgrp = lane >> 4;       // k group
    const int colbase = w * 64;
    f32x4 acc[4][4] = {};

    for (int ks = 0; ks < 11; ++ks) {
        const int k0 = ks * 32 + kgrp * 8;
        bf16x8 bfr[4], afr[4];
#pragma unroll
        for (int n = 0; n < 4; ++n)
            bfr[n] = *(const bf16x8*)&Wt[(size_t)(colbase + n * 16 + arow) * 352 + k0];
#pragma unroll
        for (int m = 0; m < 4; ++m)
            afr[m] = *(const bf16x8*)&lds[(m * 16 + arow) * LDSROW + k0];
#pragma unroll
        for (int m = 0; m < 4; ++m)
#pragma unroll
            for (int n = 0; n < 4; ++n)
                acc[m][n] = __builtin_amdgcn_mfma_f32_16x16x32_bf16(afr[m], bfr[n],
                                                                    acc[m][n], 0, 0, 0);
    }

    // ---- fp32 epilogue: per-lane partial y/z over its 4 cols, reduce 16 lanes ----
    float b1c[4];
    float2 wl[4], wr[4];
#pragma unroll
    for (int n = 0; n < 4; ++n) {
        int c = colbase + n * 16 + arow;
        b1c[n] = b1[c];
        wl[n] = *(const float2*)&W2l[c * 2];
        wr[n] = *(const float2*)&W2r[c * 2];
    }
    __syncthreads();                 // all waves done reading A-tile
    float* part = (float*)lds;       // part[w][row][4] : 4*64*4 floats = 4 KB

#pragma unroll
    for (int m = 0; m < 4; ++m)
#pragma unroll
        for (int r = 0; r < 4; ++r) {
            float y0 = 0.f, y1 = 0.f, z0 = 0.f, z1 = 0.f;
#pragma unroll
            for (int n = 0; n < 4; ++n) {
                float h = fmaxf(acc[m][n][r] + b1c[n], 0.0f);
                y0 = fmaf(h, wl[n].x, y0); y1 = fmaf(h, wl[n].y, y1);
                z0 = fmaf(h, wr[n].x, z0); z1 = fmaf(h, wr[n].y, z1);
            }
#pragma unroll
            for (int off = 1; off < 16; off <<= 1) {
                y0 += __shfl_xor(y0, off); y1 += __shfl_xor(y1, off);
                z0 += __shfl_xor(z0, off); z1 += __shfl_xor(z1, off);
            }
            if (arow == 0) {
                int row = m * 16 + kgrp * 4 + r;
                float* p = &part[(w * 64 + row) * 4];
                p[0] = y0; p[1] = y1; p[2] = z0; p[3] = z1;
            }
        }
    __syncthreads();

    // cross-wave sum: 256 threads = 64 rows x 4 channels
    {
        int row = tid >> 2;
        int ch = tid & 3;
        float s = part[row * 4 + ch] + part[(256 + row * 4) + ch] +
                  part[(512 + row * 4) + ch] + part[(768 + row * 4) + ch];
        int node = node0 + row;
        if (node < N_NODES) yz[(size_t)node * 4 + ch] = s;
    }
}

// one wave per node: out = mean(y[neighbors]) + b2 + z[node]
__global__ void k_layer2(const int* __restrict__ rowptr, const int* __restrict__ csr,
                         const float* __restrict__ yz, const float* __restrict__ b2,
                         float* __restrict__ out) {
    int n = (blockIdx.x * blockDim.x + threadIdx.x) >> 6;
    if (n >= N_NODES) return;
    const int lane = threadIdx.x & 63;
    int beg = rowptr[n], end = rowptr[n + 1];
    float y0 = 0.f, y1 = 0.f;
    for (int i = beg + lane; i < end; i += 64) {
        int s = csr[i];
        float2 v = *(const float2*)&yz[(size_t)s * 4];
        y0 += v.x; y1 += v.y;
    }
#pragma unroll
    for (int off = 32; off >= 1; off >>= 1) {
        y0 += __shfl_xor(y0, off);
        y1 += __shfl_xor(y1, off);
    }
    if (lane == 0) {
        float invd = 1.0f / fmaxf((float)(end - beg), 1.0f);
        float2 o;
        o.x = y0 * invd + b2[0] + yz[(size_t)n * 4 + 2];
        o.y = y1 * invd + b2[1] + yz[(size_t)n * 4 + 3];
        *(float2*)&out[n * 2] = o;
    }
}

extern "C" void kernel_launch(void* const* d_in, const int* in_sizes, int n_in,
                              void* d_out, int out_size, void* d_ws, size_t ws_size,
                              hipStream_t stream) {
    const float* x   = (const float*)d_in[0];
    const int*   ei  = (const int*)d_in[1];
    const int*   src = ei;
    const int*   dst = ei + N_EDGES;
    const float* W1l = (const float*)d_in[2];
    const float* b1  = (const float*)d_in[3];
    const float* W1r = (const float*)d_in[4];
    const float* W2l = (const float*)d_in[5];
    const float* b2  = (const float*)d_in[6];
    const float* W2r = (const float*)d_in[7];
    float* out = (float*)d_out;

    int* wsi = (int*)d_ws;
    int* csr    = wsi;                                   // 1.6M ints
    int* rowptr = wsi + 1600000;                         // 100001 ints
    unsigned short* xb   = (unsigned short*)(wsi + 1700004);
    unsigned short* aggb = xb + (size_t)N_NODES * XPAD;
    unsigned short* Wt   = aggb + (size_t)N_NODES * XPAD;
    float* yz            = (float*)(Wt + 256 * 352);
    // overlays (dead before k_gemm1 writes yz):
    int* deg    = (int*)yz;
    int* inccur = (int*)yz + N_NODES;    // scan1 incl -> scan3 cursor
    int* btot   = (int*)yz + 2 * N_NODES;

    hipMemsetAsync(deg, 0, N_NODES * sizeof(int), stream);

    k_cvt<<<(N_NODES * 42 + 255) / 256, 256, 0, stream>>>(x, dst, (uint2*)xb, deg);
    k_wt<<<352, 256, 0, stream>>>(W1l, W1r, Wt);
    k_scan1<<<NBLK_SCAN, 1024, 0, stream>>>(deg, inccur, btot);
    k_scan2<<<1, 64, 0, stream>>>(btot);
    k_scan3<<<NBLK_SCAN, 1024, 0, stream>>>(deg, inccur, btot, rowptr);
    k_fill<<<FILL_GRID, 256, 0, stream>>>(src, dst, inccur, csr);
    k_agg1b<<<(N_NODES * 64 + 255) / 256, 256, 0, stream>>>(rowptr, csr,
                                                            (const uint2*)xb,
                                                            (uint2*)aggb);
    k_gemm1<<<(N_NODES + 63) / 64, 256, 0, stream>>>(aggb, xb, Wt, b1, W2l, W2r, yz);
    k_layer2<<<(N_NODES * 64 + 255) / 256, 256, 0, stream>>>(rowptr, csr, yz, b2, out);
}